// Round 3
// baseline (90.409 us; speedup 1.0000x reference)
//
#include <hip/hip_runtime.h>
#include <stdint.h>

#define N_EXPERTS 20
#define DIM 32
#define TMOE 512
#define MSTR 1032   // shorts per expert in LDS (1024 + 8 pad -> 16B-aligned, bank-spread)

static __device__ __forceinline__ short f2bf(float f) {
    union { float f; uint32_t u; } v; v.f = f;
    uint32_t u = v.u;
    return (short)(uint16_t)((u + 0x7FFFu + ((u >> 16) & 1u)) >> 16);  // RNE
}
static __device__ __forceinline__ float bfl(uint32_t u) {
    union { uint32_t u; float f; } v; v.u = u << 16; return v.f;
}
static __device__ __forceinline__ float bfh(uint32_t u) {
    union { uint32_t u; float f; } v; v.u = u & 0xFFFF0000u; return v.f;
}

// ---------------- K1: combined-weight precompute ----------------
// M[e] = W0[e] @ W1[e]  (bf16), c[e] = W0[e] @ b1[e] + b0[e]  (fp32)
__global__ __launch_bounds__(256) void k_prep(
    const float* __restrict__ W1, const float* __restrict__ b1,
    const float* __restrict__ W0, const float* __restrict__ b0,
    unsigned short* __restrict__ Mbf, float* __restrict__ cvec)
{
    __shared__ float s1[1024], s0[1024];
    int e = blockIdx.x, t = threadIdx.x;
    const float* w1 = W1 + e * 1024;
    const float* w0 = W0 + e * 1024;
    for (int i = t; i < 1024; i += 256) { s1[i] = w1[i]; s0[i] = w0[i]; }
    __syncthreads();
    for (int idx = t; idx < 1024; idx += 256) {
        int o = idx >> 5, i = idx & 31;
        float s = 0.f;
        #pragma unroll
        for (int k = 0; k < 32; k++) s += s0[o*32 + k] * s1[k*32 + i];
        Mbf[e*1024 + o*32 + i] = (unsigned short)f2bf(s);
    }
    if (t < DIM) {
        float s = b0[e*32 + t];
        #pragma unroll
        for (int k = 0; k < 32; k++) s += s0[t*32 + k] * b1[e*32 + k];
        cvec[e*32 + t] = s;
    }
}

// ---------------- K2: one thread = one sample, VALU matvec + normalize ----------------
__global__ __launch_bounds__(TMOE) void k_moe(
    const float* __restrict__ x, const int* __restrict__ pos,
    const unsigned short* __restrict__ Mbf, const float* __restrict__ cvec,
    float* __restrict__ out, int B)
{
    __shared__ unsigned short Ms[N_EXPERTS * MSTR];   // 41,280 B
    __shared__ float cs[N_EXPERTS * DIM];             // 2,560 B

    int t = threadIdx.x;
    int s = blockIdx.x * TMOE + t;

    // Prefetch x + pos into registers BEFORE the staging barrier (global pipe
    // overlaps the LDS staging).
    float4 xv[8];
    int e = 0;
    bool live = (s < B);
    if (live) {
        const float4* xp = (const float4*)(x + (size_t)s * 32);
        #pragma unroll
        for (int i = 0; i < 8; i++) xv[i] = xp[i];
        e = pos[s];
    }

    // Stage all experts' M (bf16) + c (f32) into LDS. 20*128 uint4 chunks.
    {
        const uint4* msrc = (const uint4*)Mbf;
        for (int i = t; i < N_EXPERTS * 128; i += TMOE) {
            int ee = i >> 7, r = i & 127;
            uint4 v = msrc[i];
            *(uint4*)&Ms[ee * MSTR + r * 8] = v;
        }
        for (int i = t; i < N_EXPERTS * DIM; i += TMOE) cs[i] = cvec[i];
    }
    __syncthreads();
    if (!live) return;

    const unsigned short* M = Ms + e * MSTR;
    const float* c = cs + e * 32;

    float acc[32];
    #pragma unroll 4
    for (int o = 0; o < 32; o++) {
        const uint4* mp = (const uint4*)(M + o * 32);
        float a = c[o];
        #pragma unroll
        for (int kk = 0; kk < 4; kk++) {
            uint4 m = mp[kk];
            float4 x0 = xv[2*kk], x1 = xv[2*kk + 1];
            a += bfl(m.x) * x0.x + bfh(m.x) * x0.y
               + bfl(m.y) * x0.z + bfh(m.y) * x0.w
               + bfl(m.z) * x1.x + bfh(m.z) * x1.y
               + bfl(m.w) * x1.z + bfh(m.w) * x1.w;
        }
        acc[o] = a;
    }

    float ss = 0.f;
    #pragma unroll
    for (int o = 0; o < 32; o++) ss += acc[o] * acc[o];
    float sc = rsqrtf(fmaxf(ss, 1e-24f));   // == 1/max(||v||, 1e-12)

    float4* op = (float4*)(out + (size_t)s * 32);
    #pragma unroll
    for (int k = 0; k < 8; k++) {
        float4 v;
        v.x = acc[4*k + 0] * sc;
        v.y = acc[4*k + 1] * sc;
        v.z = acc[4*k + 2] * sc;
        v.w = acc[4*k + 3] * sc;
        op[k] = v;
    }
}

extern "C" void kernel_launch(void* const* d_in, const int* in_sizes, int n_in,
                              void* d_out, int out_size, void* d_ws, size_t ws_size,
                              hipStream_t stream) {
    const float* x  = (const float*)d_in[0];
    const float* W1 = (const float*)d_in[1];
    const float* b1 = (const float*)d_in[2];
    const float* W0 = (const float*)d_in[3];
    const float* b0 = (const float*)d_in[4];
    const int*  pos = (const int*)d_in[5];
    float* out = (float*)d_out;
    int B = in_sizes[0] / DIM;   // 131072

    char* ws = (char*)d_ws;
    unsigned short* Mbf = (unsigned short*)ws;                       // 20*1024 shorts
    float* cvec = (float*)(ws + (size_t)N_EXPERTS * 1024 * 2);       // 20*32 floats

    k_prep<<<N_EXPERTS, 256, 0, stream>>>(W1, b1, W0, b0, Mbf, cvec);
    int nblk = (B + TMOE - 1) / TMOE;
    k_moe<<<nblk, TMOE, 0, stream>>>(x, pos, Mbf, cvec, out, B);
}